// Round 1
// baseline (140.366 us; speedup 1.0000x reference)
//
#include <hip/hip_runtime.h>

// LIF spike recurrence:
//   u_t = u_{t-1} - Vth * o_{t-1} + x_t ;  o_t = (u_t > Vth) ? 1 : 0
// x: [T=16, N=B*C*H*W] float32, out: same shape float32.
// Each thread owns 4 consecutive spatial elements (float4) and loops over T
// keeping (u, o) in registers. Memory-bound: 256 MiB read + 256 MiB write.

#define LIF_VTH   1.0f
#define LIF_STEPS 16

__global__ __launch_bounds__(256) void LIFSpike_84542136254876_kernel(
    const float4* __restrict__ x, float4* __restrict__ out, int n4) {
    int i = blockIdx.x * blockDim.x + threadIdx.x;
    if (i >= n4) return;

    float4 u = make_float4(0.f, 0.f, 0.f, 0.f);
    float4 o = make_float4(0.f, 0.f, 0.f, 0.f);

#pragma unroll
    for (int t = 0; t < LIF_STEPS; ++t) {
        float4 xt = x[(size_t)t * (size_t)n4 + (size_t)i];
        u.x = u.x - o.x + xt.x;  o.x = (u.x > LIF_VTH) ? 1.0f : 0.0f;
        u.y = u.y - o.y + xt.y;  o.y = (u.y > LIF_VTH) ? 1.0f : 0.0f;
        u.z = u.z - o.z + xt.z;  o.z = (u.z > LIF_VTH) ? 1.0f : 0.0f;
        u.w = u.w - o.w + xt.w;  o.w = (u.w > LIF_VTH) ? 1.0f : 0.0f;
        out[(size_t)t * (size_t)n4 + (size_t)i] = o;
    }
}

extern "C" void kernel_launch(void* const* d_in, const int* in_sizes, int n_in,
                              void* d_out, int out_size, void* d_ws, size_t ws_size,
                              hipStream_t stream) {
    const float* x = (const float*)d_in[0];
    float* out = (float*)d_out;

    int total = in_sizes[0];          // T * N
    int n = total / LIF_STEPS;        // spatial elements per timestep
    int n4 = n / 4;                   // float4 elements per timestep

    int block = 256;
    int grid = (n4 + block - 1) / block;

    LIFSpike_84542136254876_kernel<<<grid, block, 0, stream>>>(
        (const float4*)x, (float4*)out, n4);
}

// Round 3
// 91.446 us; speedup vs baseline: 1.5350x; 1.5350x over previous
//
#include <hip/hip_runtime.h>

// LIF spike recurrence:
//   u_t = u_{t-1} - Vth * o_{t-1} + x_t ;  o_t = (u_t > Vth) ? 1 : 0
// x: [T=16, N=4194304] float32, out: same shape float32.
//
// Each thread owns 4 consecutive floats (native float4 vector). It first
// issues ALL 16 time-plane loads into a statically-indexed register array
// (16 independent global_load_dwordx4 in flight -> deep MLP to cover ~900cy
// HBM latency), then runs the recurrence and writes the 16 outputs with
// nontemporal stores (keeps x L3-resident across replays).

#define LIF_VTH   1.0f
#define LIF_STEPS 16

typedef float fx4 __attribute__((ext_vector_type(4)));

__global__ __launch_bounds__(256) void LIFSpike_84542136254876_kernel(
    const fx4* __restrict__ x, fx4* __restrict__ out, int n4) {
    int i = blockIdx.x * blockDim.x + threadIdx.x;
    if (i >= n4) return;

    // Phase 1: issue all 16 loads (independent; stay in flight together).
    fx4 xt[LIF_STEPS];
#pragma unroll
    for (int t = 0; t < LIF_STEPS; ++t) {
        xt[t] = x[(size_t)t * (size_t)n4 + (size_t)i];
    }

    // Phase 2: recurrence + stores.
    fx4 u = (fx4)0.0f;
    fx4 o = (fx4)0.0f;
#pragma unroll
    for (int t = 0; t < LIF_STEPS; ++t) {
        u = u - o + xt[t];
        fx4 on;
        on.x = (u.x > LIF_VTH) ? 1.0f : 0.0f;
        on.y = (u.y > LIF_VTH) ? 1.0f : 0.0f;
        on.z = (u.z > LIF_VTH) ? 1.0f : 0.0f;
        on.w = (u.w > LIF_VTH) ? 1.0f : 0.0f;
        o = on;
        __builtin_nontemporal_store(o, &out[(size_t)t * (size_t)n4 + (size_t)i]);
    }
}

extern "C" void kernel_launch(void* const* d_in, const int* in_sizes, int n_in,
                              void* d_out, int out_size, void* d_ws, size_t ws_size,
                              hipStream_t stream) {
    const float* x = (const float*)d_in[0];
    float* out = (float*)d_out;

    int total = in_sizes[0];          // T * N
    int n = total / LIF_STEPS;        // spatial elements per timestep
    int n4 = n / 4;                   // float4 elements per timestep

    int block = 256;
    int grid = (n4 + block - 1) / block;

    LIFSpike_84542136254876_kernel<<<grid, block, 0, stream>>>(
        (const fx4*)x, (fx4*)out, n4);
}